// Round 19
// baseline (102.197 us; speedup 1.0000x reference)
//
#include <hip/hip_runtime.h>
#include <hip/hip_bf16.h>

#define LOG2PI_F 1.8378770664093453f
#define LOG2E_F  1.44269504f

typedef float f32x4 __attribute__((ext_vector_type(4)));
typedef short s16x8 __attribute__((ext_vector_type(8)));
typedef unsigned short u16;

// ---- workspace layout (float offsets into d_ws) ----
#define OFF_PREC   0        // f32 [8][16][16]
#define OFF_LOGDET 2048     // f32 [8]
#define OFF_LTR    2064     // f32 [8][8]   log(softmax(T)+1e-8) * log2e
#define OFF_LINI   2128     // f32 [8]      log softmax(init)    * log2e
#define OFF_CHAIN  2144     // int [8][16]
#define OFF_CNT    2272     // int [8]      bucket counts
#define OFF_PERM   2304     // int [8][512] bucketed batch ids (ends 6400)
#define OFF_FLAG   6656     // int [512]    per-batch argmax state
#define OFF_ELL    8192     // f32 [512][8][128]  (scaled by log2e)  [b][s][f]
#define OFF_WT     532480   // u16(bf16) [8][128][16][16]  Wt[s][l][d][c]

__device__ inline u16 f2bf(float x) {
  union { float f; unsigned u; } v; v.f = x;
  unsigned r = v.u + 0x7fffu + ((v.u >> 16) & 1u);  // RNE
  return (u16)(r >> 16);
}

__device__ inline float fexp2(float x) {
#if __has_builtin(__builtin_amdgcn_exp2f)
  return __builtin_amdgcn_exp2f(x);          // raw v_exp_f32
#else
  return exp2f(x);
#endif
}

// ---------------------------------------------------------------------------
// kernel 1: blocks 0..1023 build Wt(bf16); block 1024 does prep (eps-free:
// prec = C^-T C^-1, logdet = 2*sum(diag cc))
// ---------------------------------------------------------------------------
__global__ __launch_bounds__(256) void prep_wt_kernel(const float* __restrict__ tmat,
                                                      const float* __restrict__ initd,
                                                      const float* __restrict__ cc,
                                                      const float* __restrict__ W,
                                                      float* __restrict__ ws) {
  __shared__ float Ls[8][16][16];
  __shared__ float tmp[256];
  int t = threadIdx.x;

  if (blockIdx.x < 1024) {                       // ---- Wt build ----
    u16* Wt = (u16*)(ws + OFF_WT);
    int sl = blockIdx.x;
    tmp[t] = W[sl * 256 + t];
    __syncthreads();
    int d = t >> 4, c = t & 15;
    Wt[sl * 256 + t] = f2bf(tmp[c * 16 + d]);    // out[d][c] = in[c][d]
    return;
  }

  // ---- prep ----
  float* prec   = ws + OFF_PREC;
  float* logdet = ws + OFF_LOGDET;
  float* ltr    = ws + OFF_LTR;
  float* lini   = ws + OFF_LINI;
  int*   chain  = (int*)(ws + OFF_CHAIN);

  if (t < 128) {                                 // chol = tril(cc,-1)+diag(exp(diag))
    int s = t >> 4, i = t & 15;
    const float* c0 = cc + s * 256 + i * 16;
    for (int j = 0; j < 16; ++j) {
      float v = c0[j];
      Ls[s][i][j] = (i > j) ? v : (i == j ? expf(v) : 0.f);
    }
  } else if (t < 136) {                          // logdet = 2*sum(diag cc) (eps-free)
    int s = t - 128;
    float ld = 0.f;
    for (int i = 0; i < 16; ++i) ld += cc[s * 256 + i * 17];
    logdet[s] = 2.f * ld;
  } else if (t == 136) {
    float m = -1e30f;
    for (int i = 0; i < 8; ++i) m = fmaxf(m, initd[i]);
    float sum = 0.f;
    for (int i = 0; i < 8; ++i) sum += expf(initd[i] - m);
    float lsum = logf(sum);
    for (int i = 0; i < 8; ++i) lini[i] = (initd[i] - m - lsum) * LOG2E_F;
  } else if (t == 137) {
    int nxt[8];
    for (int i = 0; i < 8; ++i) {
      float best = -1e30f; int bi = 0;
      for (int j = 0; j < 8; ++j) {
        float v = tmat[i * 8 + j];
        if (v > best) { best = v; bi = j; }      // first-max rule
      }
      nxt[i] = bi;
    }
    for (int s0 = 0; s0 < 8; ++s0) {
      int c = s0;
      for (int k = 0; k < 16; ++k) { c = nxt[c]; chain[s0 * 16 + k] = c; }
    }
  } else if (t >= 144 && t < 152) {
    int i = t - 144;
    float m = -1e30f;
    for (int j = 0; j < 8; ++j) m = fmaxf(m, tmat[i * 8 + j]);
    float sum = 0.f;
    for (int j = 0; j < 8; ++j) sum += expf(tmat[i * 8 + j] - m);
    for (int j = 0; j < 8; ++j)
      ltr[i * 8 + j] = logf(expf(tmat[i * 8 + j] - m) / sum + 1e-8f) * LOG2E_F;
  }
  __syncthreads();
  if (t < 128) {                                 // prec = C^-T C^-1
    int s = t >> 4, col = t & 15;
    float y[16], x[16];
#pragma unroll
    for (int i = 0; i < 16; ++i) {
      float v = (i == col) ? 1.f : 0.f;
#pragma unroll
      for (int k = 0; k < 16; ++k) if (k < i) v -= Ls[s][i][k] * y[k];
      y[i] = v / Ls[s][i][i];
    }
#pragma unroll
    for (int i = 15; i >= 0; --i) {
      float v = y[i];
#pragma unroll
      for (int k = 0; k < 16; ++k) if (k > i) v -= Ls[s][k][i] * x[k];
      x[i] = v / Ls[s][i][i];
    }
#pragma unroll
    for (int i = 0; i < 16; ++i) prec[s * 256 + i * 16 + col] = x[i];
  }
}

// ---------------------------------------------------------------------------
// emis v7 (r14 proven): state-pair x 4 batches, 512x512, 40 KB LDS,
// 2 blocks/CU = 16 waves/CU. Wave w owns ONE m-tile mt=(w<4?w:11-w).
// ---------------------------------------------------------------------------
__global__ __launch_bounds__(512, 4) void emis_kernel(const float* __restrict__ emis,
                                                      const float* __restrict__ means,
                                                      float* __restrict__ ws) {
  const float* prec   = ws + OFF_PREC;
  const float* logdet = ws + OFF_LOGDET;
  const u16* Wt = (const u16*)(ws + OFF_WT);
  float* ell = ws + OFF_ELL;

  int sp = blockIdx.x & 3;
  int bg = blockIdx.x >> 2;
  int s0 = sp * 2;
  int bb0 = bg * 4;
  int tid = threadIdx.x;

  __shared__ __align__(16) char smem[40960];     // padh[4][256][16] u16 (32 KB)
  char* pbase = smem;                            // ... then diffL[4][128][20] f32
  float* dlf = (float*)smem;
  const s16x8 zero8 = {0, 0, 0, 0, 0, 0, 0, 0};

  for (int i = tid; i < 1024; i += 512)          // zero rows 0..127, 4 planes
    *(s16x8*)(pbase + (i >> 8) * 8192 + (i & 255) * 16) = zero8;
  for (int i = tid; i < 1024; i += 512) {        // stage rows 128..255, swizzled
    int g = i >> 8, erow = (i >> 1) & 127, h2 = i & 1;
    const f32x4* src = (const f32x4*)(emis + (size_t)(bb0 + g) * 2048 + erow * 16 + h2 * 8);
    f32x4 v0 = src[0], v1 = src[1];
    s16x8 pk;
#pragma unroll
    for (int c = 0; c < 4; ++c) { pk[c] = (short)f2bf(v0[c]); pk[c + 4] = (short)f2bf(v1[c]); }
    int row = 128 + erow;
    int off = ((row << 5) + (h2 << 4)) ^ (((row >> 2) & 3) << 4);
    *(s16x8*)(pbase + g * 8192 + off) = pk;
  }
  __syncthreads();

  int wave = tid >> 6, lane = tid & 63;
  int mt = (wave < 4) ? wave : 11 - wave;        // balanced SIMD pairing
  int rc = lane & 15;
  int h  = (lane >> 4) & 1;
  int dl = lane >> 5;
  int hh = h << 4;
  int kst = 56 - 8 * mt;
  int r0 = mt * 16 + rc + dl;

  const u16* Bp0 = Wt + ((size_t)((s0 * 128 + dl) * 16 + rc) * 16) + h * 8 + (size_t)kst * 512;
  const u16* Bp1 = Bp0 + 32768;

  f32x4 acc[2][4] = {};
  s16x8 w0 = *(const s16x8*)Bp0, w1 = *(const s16x8*)Bp1;
  for (int kk = kst; kk < 64; ++kk) {
    s16x8 n0, n1;
    if (kk < 63) { n0 = *(const s16x8*)(Bp0 + 512); n1 = *(const s16x8*)(Bp1 + 512); }
    Bp0 += 512; Bp1 += 512;
    int row = r0 + 2 * kk;
    const char* pa = pbase + (((row << 5) + hh) ^ (((row >> 2) & 3) << 4));
#pragma unroll
    for (int g = 0; g < 4; ++g) {
      s16x8 a = *(const s16x8*)(pa + g * 8192);
      acc[0][g] = __builtin_amdgcn_mfma_f32_16x16x32_bf16(a, w0, acc[0][g], 0, 0, 0);
      acc[1][g] = __builtin_amdgcn_mfma_f32_16x16x32_bf16(a, w1, acc[1][g], 0, 0, 0);
    }
    w0 = n0; w1 = n1;
  }

  int hi = (lane >> 4) & 3;
  float ev[4][4];
#pragma unroll
  for (int g = 0; g < 4; ++g)
#pragma unroll
    for (int r = 0; r < 4; ++r)
      ev[g][r] = emis[(size_t)(bb0 + g) * 2048 + (mt * 16 + hi * 4 + r) * 16 + rc];

  __syncthreads();                               // Hankel tile dead -> overlay diffL

#pragma unroll
  for (int s = 0; s < 2; ++s) {
    float mn = means[(s0 + s) * 16 + rc];
#pragma unroll
    for (int g = 0; g < 4; ++g) {
#pragma unroll
      for (int r = 0; r < 4; ++r) {
        int f = mt * 16 + hi * 4 + r;
        dlf[(g * 128 + f) * 20 + rc] = ev[g][r] - acc[s][g][r] - mn;
      }
    }
    __syncthreads();
    const float* P = prec + (s0 + s) * 256;      // block-uniform -> scalar loads
    float c2 = -0.72134752f * (logdet[s0 + s] + 16.f * LOG2PI_F);
    {
      int g = tid >> 7, f = tid & 127;           // 512 tasks = 4 batches x 128 f
      float dv[16];
#pragma unroll
      for (int c = 0; c < 4; ++c)
        *(f32x4*)&dv[c * 4] = *(const f32x4*)&dlf[(g * 128 + f) * 20 + c * 4];
      float qq = 0.f;
#pragma unroll
      for (int c = 0; c < 16; ++c) {
        float tsum = 0.5f * P[c * 16 + c] * dv[c];
#pragma unroll
        for (int d2 = 0; d2 < 16; ++d2)
          if (d2 > c) tsum = fmaf(P[c * 16 + d2], dv[d2], tsum);
        qq = fmaf(dv[c], tsum, qq);
      }
      ell[((size_t)(bb0 + g) * 8 + s0 + s) * 128 + f] = fmaf(-2.f * 0.72134752f, qq, c2);
    }
    if (s == 0) __syncthreads();
  }
}

// ---------------------------------------------------------------------------
// fwd v8 = v7 body, but the terminal device atomic is replaced by a plain
// flag[b] store (the 512-block same-line atomic burst serializes at L2 and
// was the tree-version-independent ~15us tail). Bucketing moved to
// bucket_kernel (deterministic, no atomics).
// ---------------------------------------------------------------------------
__global__ __launch_bounds__(256) void fwd_kernel(float* __restrict__ ws) {
  const float* ell  = ws + OFF_ELL;
  const float* ltr  = ws + OFF_LTR;
  const float* lini = ws + OFF_LINI;
  int* flag = (int*)(ws + OFF_FLAG);

  __shared__ float leaf[128 * 68];     // 34 KB (stride-68 matrices)
  __shared__ float lvl[64 * 68];       // 17 KB
  __shared__ float ebuf[1024];         // 4 KB: ell[b] = [s][f]
  __shared__ float LTs[64];
  __shared__ float kmax[128];
  __shared__ float redv[8];

  int b = blockIdx.x, tid = threadIdx.x;

  *(f32x4*)&ebuf[tid * 4] = *(const f32x4*)(ell + (size_t)b * 1024 + tid * 4);
  if (tid < 64) LTs[tid] = ltr[tid];
  __syncthreads();

  if (tid < 128) {                     // per-leaf column max (leaf m uses e_{m+1})
    int m = tid;
    float mx = 0.f;
    if (m < 127) {
      mx = -1e30f;
#pragma unroll
      for (int j = 0; j < 8; ++j) mx = fmaxf(mx, ebuf[j * 128 + m + 1]);
    }
    kmax[m] = mx;
  }
  __syncthreads();

  for (int t = tid; t < 8192; t += 256) {   // leaves (linear, exp2 here only)
    int m = t >> 6, i = (t >> 3) & 7, j = t & 7;
    float v;
    if (m < 127) v = fexp2(LTs[i * 8 + j] + ebuf[j * 128 + (m + 1)] - kmax[m]);
    else         v = (i == j) ? 1.f : 0.f;  // identity pad
    leaf[m * 68 + i * 8 + j] = v;
  }
  __syncthreads();

  float* src = leaf;
  float* dst = lvl;
  int nm = 64;
  for (int level = 0; level < 7; ++level) {
    for (int t = tid; t < nm * 8; t += 256) {   // task = one output ROW
      int p = t >> 3, i = t & 7;
      const float* Ma = src + (p * 2) * 68 + i * 8;
      const float* Mb = src + (p * 2 + 1) * 68;
      float av[8];
      *(f32x4*)&av[0] = *(const f32x4*)&Ma[0];
      *(f32x4*)&av[4] = *(const f32x4*)&Ma[4];
      float B[8][8];                            // 64 VGPR, static-indexed
#pragma unroll
      for (int k = 0; k < 8; ++k) {
        *(f32x4*)&B[k][0] = *(const f32x4*)&Mb[k * 8];
        *(f32x4*)&B[k][4] = *(const f32x4*)&Mb[k * 8 + 4];
      }
      float outv[8];
#pragma unroll
      for (int j = 0; j < 8; ++j) {
        float sum = 0.f;
#pragma unroll
        for (int k = 0; k < 8; ++k) sum = fmaf(av[k], B[k][j], sum);
        outv[j] = sum;
      }
      // per-matrix rescale: rows of matrix p live in an aligned 8-lane group
      float rm = outv[0];
#pragma unroll
      for (int j = 1; j < 8; ++j) rm = fmaxf(rm, outv[j]);
      rm = fmaxf(rm, __shfl_xor(rm, 1));
      rm = fmaxf(rm, __shfl_xor(rm, 2));
      rm = fmaxf(rm, __shfl_xor(rm, 4));
      int ex = (int)((__float_as_uint(rm) >> 23) & 0xFFu) - 127;
#pragma unroll
      for (int j = 0; j < 8; ++j) outv[j] = ldexpf(outv[j], -ex);
      *(f32x4*)&dst[p * 68 + i * 8]     = *(f32x4*)&outv[0];
      *(f32x4*)&dst[p * 68 + i * 8 + 4] = *(f32x4*)&outv[4];
    }
    __syncthreads();
    float* tswap = src; src = dst; dst = tswap;
    nm >>= 1;
  }
  // rescaled product matrix P in src[0..63]

  if (tid < 8) {                        // v[s] = sum_i exp2(la0[i]-k0) * P[i][s]
    int s = tid;
    float k0 = -1e30f;
#pragma unroll
    for (int i = 0; i < 8; ++i) k0 = fmaxf(k0, lini[i] + ebuf[i * 128]);
    float v = 0.f;
#pragma unroll
    for (int i = 0; i < 8; ++i)
      v = fmaf(fexp2(lini[i] + ebuf[i * 128] - k0), src[i * 8 + s], v);
    redv[s] = v;
  }
  __syncthreads();
  if (tid == 0) {
    float best = -1e30f; int bi = 0;
#pragma unroll
    for (int i = 0; i < 8; ++i) {
      float o = redv[i];
      if (o > best) { best = o; bi = i; }   // first-max (monotone map preserves)
    }
    flag[b] = bi;                           // plain store; no atomic
  }
}

// ---------------------------------------------------------------------------
// bucket: single block builds cnt/perm from flag deterministically (no atomics)
// ---------------------------------------------------------------------------
__global__ __launch_bounds__(64) void bucket_kernel(float* __restrict__ ws) {
  const int* flag = (const int*)(ws + OFF_FLAG);
  int* cnt  = (int*)(ws + OFF_CNT);
  int* perm = (int*)(ws + OFF_PERM);
  __shared__ int fl[512];
  int tid = threadIdx.x;
  for (int i = tid; i < 512; i += 64) fl[i] = flag[i];
  __syncthreads();
  if (tid < 8) {                       // lane = bucket; batch-ascending order
    int c = 0;
    for (int b = 0; b < 512; ++b)
      if (fl[b] == tid) { perm[tid * 512 + c] = b; ++c; }
    cnt[tid] = c;
  }
}

// ---------------------------------------------------------------------------
// pred v4 (r14 proven): 8-wave split-K, registers hold outputs.
// ---------------------------------------------------------------------------
__global__ __launch_bounds__(512, 2) void pred_kernel(const float* __restrict__ emis,
                                                      const float* __restrict__ means,
                                                      float* __restrict__ ws,
                                                      float* __restrict__ out) {
  const int* chain = (const int*)(ws + OFF_CHAIN);
  const int* cnt   = (const int*)(ws + OFF_CNT);
  const int* perm  = (const int*)(ws + OFF_PERM);
  const u16* Wt = (const u16*)(ws + OFF_WT);

  __shared__ u16 buf[16][128][16];     // 64 KB bf16 lag buffers, batch-XOR swizzled
  __shared__ float part[8][64][4];     // 8 KB wave partials
  __shared__ float ms[8][16];
  __shared__ int bid[16];

  int bucket = blockIdx.x >> 5, slot = blockIdx.x & 31;
  int nb = cnt[bucket];
  int base = slot * 16;
  if (base >= nb) return;              // block-uniform -> safe before barriers
  int tid = threadIdx.x;
  char* pb = (char*)&buf[0][0][0];

  if (tid < 16) {
    int idx = base + tid;
    bid[tid] = perm[bucket * 512 + (idx < nb ? idx : base)];  // pad = dup first
  } else if (tid >= 128 && tid < 256) {
    int t2 = tid - 128;
    ms[t2 >> 4][t2 & 15] = means[t2];
  }
  __syncthreads();

  for (int i = tid; i < 2048; i += 512) {
    int b = i >> 7, row = i & 127;
    const f32x4* sp = (const f32x4*)(emis + (size_t)bid[b] * 2048 + row * 16);
    f32x4 v0 = sp[0], v1 = sp[1], v2 = sp[2], v3 = sp[3];
    s16x8 p0, p1;
#pragma unroll
    for (int j = 0; j < 4; ++j) {
      p0[j] = (short)f2bf(v0[j]); p0[4 + j] = (short)f2bf(v1[j]);
      p1[j] = (short)f2bf(v2[j]); p1[4 + j] = (short)f2bf(v3[j]);
    }
    int xo = (b & 7) << 4;
    int bse = b * 4096 + row * 32;
    *(s16x8*)(pb + (bse ^ xo)) = p0;
    *(s16x8*)(pb + ((bse + 16) ^ xo)) = p1;
  }
  __syncthreads();

  int wave = tid >> 6, lane = tid & 63;
  int rc = lane & 15;                  // A: batch | B/C: d
  int q  = lane >> 4;
  int h  = q & 1;
  int dl = q >> 1;
  int axor = (rc & 7) << 4;
  const int* mychain = chain + bucket * 16;
  int b_own = q * 4 + (wave & 3);      // waves 0..3 own outputs
  int bown_base = b_own * 4096;
  int bown_xor = (b_own & 7) << 4;

  float outv[16];
  int start = 0;
#pragma unroll
  for (int k = 0; k < 16; ++k) {
    int st = mychain[k];
    const u16* Bb = Wt + ((size_t)((st * 128 + dl) * 16 + rc) * 16) + h * 8;
    f32x4 accA = {0.f, 0.f, 0.f, 0.f}, accB = {0.f, 0.f, 0.f, 0.f};
#pragma unroll
    for (int t2 = 0; t2 < 4; ++t2) {
      int kkA = wave * 8 + t2 * 2, kkB = kkA + 1;
      s16x8 wA = *(const s16x8*)(Bb + (size_t)kkA * 512);
      s16x8 wB2 = *(const s16x8*)(Bb + (size_t)kkB * 512);
      int rowA = (start + kkA * 2 + dl) & 127;
      int rowB = (start + kkB * 2 + dl) & 127;
      s16x8 aA = *(const s16x8*)(pb + ((rc * 4096 + rowA * 32 + h * 16) ^ axor));
      s16x8 aB = *(const s16x8*)(pb + ((rc * 4096 + rowB * 32 + h * 16) ^ axor));
      accA = __builtin_amdgcn_mfma_f32_16x16x32_bf16(aA, wA, accA, 0, 0, 0);
      accB = __builtin_amdgcn_mfma_f32_16x16x32_bf16(aB, wB2, accB, 0, 0, 0);
    }
    f32x4 acc = accA + accB;
    *(f32x4*)&part[wave][lane][0] = acc;
    __syncthreads();
    if (wave < 4) {
      f32x4 cs = (*(f32x4*)&part[0][lane][0] + *(f32x4*)&part[1][lane][0])
               + (*(f32x4*)&part[2][lane][0] + *(f32x4*)&part[3][lane][0]);
      f32x4 cs2 = (*(f32x4*)&part[4][lane][0] + *(f32x4*)&part[5][lane][0])
                + (*(f32x4*)&part[6][lane][0] + *(f32x4*)&part[7][lane][0]);
      cs = cs + cs2;
      float vown = (wave & 3) == 0 ? cs[0] : (wave & 3) == 1 ? cs[1]
                 : (wave & 3) == 2 ? cs[2] : cs[3];
      float o = vown + ms[st][rc];
      outv[k] = o;
      *(u16*)(pb + ((bown_base + start * 32 + rc * 2) ^ bown_xor)) = f2bf(o);
    }
    __syncthreads();
    start = (start + 1) & 127;
  }
  if (wave < 4 && base + b_own < nb) {
    float* op = out + (size_t)bid[b_own] * 256 + rc;
#pragma unroll
    for (int k = 0; k < 16; ++k) op[k * 16] = outv[k];
  }
}

extern "C" void kernel_launch(void* const* d_in, const int* in_sizes, int n_in,
                              void* d_out, int out_size, void* d_ws, size_t ws_size,
                              hipStream_t stream) {
  const float* emis  = (const float*)d_in[0];
  const float* tmat  = (const float*)d_in[1];
  const float* initd = (const float*)d_in[2];
  const float* means = (const float*)d_in[3];
  const float* cc    = (const float*)d_in[4];
  const float* W     = (const float*)d_in[5];
  float* ws  = (float*)d_ws;
  float* out = (float*)d_out;

  hipLaunchKernelGGL(prep_wt_kernel, dim3(1025), dim3(256), 0, stream, tmat, initd, cc, W, ws);
  hipLaunchKernelGGL(emis_kernel, dim3(512), dim3(512), 0, stream, emis, means, ws);
  hipLaunchKernelGGL(fwd_kernel, dim3(512), dim3(256), 0, stream, ws);
  hipLaunchKernelGGL(bucket_kernel, dim3(1), dim3(64), 0, stream, ws);
  hipLaunchKernelGGL(pred_kernel, dim3(256), dim3(512), 0, stream, emis, means, ws, out);
}

// Round 20
// 72.199 us; speedup vs baseline: 1.4155x; 1.4155x over previous
//
#include <hip/hip_runtime.h>
#include <hip/hip_bf16.h>

#define LOG2PI_F 1.8378770664093453f
#define LOG2E_F  1.44269504f

typedef float f32x4 __attribute__((ext_vector_type(4)));
typedef short s16x8 __attribute__((ext_vector_type(8)));
typedef unsigned short u16;

// ---- workspace layout (float offsets into d_ws) ----
#define OFF_PREC   0        // f32 [8][16][16]
#define OFF_LOGDET 2048     // f32 [8]
#define OFF_LTR    2064     // f32 [8][8]   log(softmax(T)+1e-8) * log2e
#define OFF_LINI   2128     // f32 [8]      log softmax(init)    * log2e
#define OFF_CHAIN  2144     // int [8][16]
#define OFF_CNT    2272     // int [8]      bucket counts
#define OFF_PERM   2304     // int [8][512] bucketed batch ids (ends 6400)
#define OFF_FLAG   6656     // int [512]    per-batch argmax state
#define OFF_ELL    8192     // f32 [512][8][128]  (scaled by log2e)  [b][s][f]
#define OFF_WT     532480   // u16(bf16) [8][128][16][16]  Wt[s][l][d][c]

__device__ inline u16 f2bf(float x) {
  union { float f; unsigned u; } v; v.f = x;
  unsigned r = v.u + 0x7fffu + ((v.u >> 16) & 1u);  // RNE
  return (u16)(r >> 16);
}

__device__ inline float fexp2(float x) {
#if __has_builtin(__builtin_amdgcn_exp2f)
  return __builtin_amdgcn_exp2f(x);          // raw v_exp_f32
#else
  return exp2f(x);
#endif
}

// ---------------------------------------------------------------------------
// kernel 1: blocks 0..1023 build Wt(bf16); block 1024 does prep (eps-free:
// prec = C^-T C^-1, logdet = 2*sum(diag cc))
// ---------------------------------------------------------------------------
__global__ __launch_bounds__(256) void prep_wt_kernel(const float* __restrict__ tmat,
                                                      const float* __restrict__ initd,
                                                      const float* __restrict__ cc,
                                                      const float* __restrict__ W,
                                                      float* __restrict__ ws) {
  __shared__ float Ls[8][16][16];
  __shared__ float tmp[256];
  int t = threadIdx.x;

  if (blockIdx.x < 1024) {                       // ---- Wt build ----
    u16* Wt = (u16*)(ws + OFF_WT);
    int sl = blockIdx.x;
    tmp[t] = W[sl * 256 + t];
    __syncthreads();
    int d = t >> 4, c = t & 15;
    Wt[sl * 256 + t] = f2bf(tmp[c * 16 + d]);    // out[d][c] = in[c][d]
    return;
  }

  // ---- prep ----
  float* prec   = ws + OFF_PREC;
  float* logdet = ws + OFF_LOGDET;
  float* ltr    = ws + OFF_LTR;
  float* lini   = ws + OFF_LINI;
  int*   chain  = (int*)(ws + OFF_CHAIN);

  if (t < 128) {                                 // chol = tril(cc,-1)+diag(exp(diag))
    int s = t >> 4, i = t & 15;
    const float* c0 = cc + s * 256 + i * 16;
    for (int j = 0; j < 16; ++j) {
      float v = c0[j];
      Ls[s][i][j] = (i > j) ? v : (i == j ? expf(v) : 0.f);
    }
  } else if (t < 136) {                          // logdet = 2*sum(diag cc) (eps-free)
    int s = t - 128;
    float ld = 0.f;
    for (int i = 0; i < 16; ++i) ld += cc[s * 256 + i * 17];
    logdet[s] = 2.f * ld;
  } else if (t == 136) {
    float m = -1e30f;
    for (int i = 0; i < 8; ++i) m = fmaxf(m, initd[i]);
    float sum = 0.f;
    for (int i = 0; i < 8; ++i) sum += expf(initd[i] - m);
    float lsum = logf(sum);
    for (int i = 0; i < 8; ++i) lini[i] = (initd[i] - m - lsum) * LOG2E_F;
  } else if (t == 137) {
    int nxt[8];
    for (int i = 0; i < 8; ++i) {
      float best = -1e30f; int bi = 0;
      for (int j = 0; j < 8; ++j) {
        float v = tmat[i * 8 + j];
        if (v > best) { best = v; bi = j; }      // first-max rule
      }
      nxt[i] = bi;
    }
    for (int s0 = 0; s0 < 8; ++s0) {
      int c = s0;
      for (int k = 0; k < 16; ++k) { c = nxt[c]; chain[s0 * 16 + k] = c; }
    }
  } else if (t >= 144 && t < 152) {
    int i = t - 144;
    float m = -1e30f;
    for (int j = 0; j < 8; ++j) m = fmaxf(m, tmat[i * 8 + j]);
    float sum = 0.f;
    for (int j = 0; j < 8; ++j) sum += expf(tmat[i * 8 + j] - m);
    for (int j = 0; j < 8; ++j)
      ltr[i * 8 + j] = logf(expf(tmat[i * 8 + j] - m) / sum + 1e-8f) * LOG2E_F;
  }
  __syncthreads();
  if (t < 128) {                                 // prec = C^-T C^-1
    int s = t >> 4, col = t & 15;
    float y[16], x[16];
#pragma unroll
    for (int i = 0; i < 16; ++i) {
      float v = (i == col) ? 1.f : 0.f;
#pragma unroll
      for (int k = 0; k < 16; ++k) if (k < i) v -= Ls[s][i][k] * y[k];
      y[i] = v / Ls[s][i][i];
    }
#pragma unroll
    for (int i = 15; i >= 0; --i) {
      float v = y[i];
#pragma unroll
      for (int k = 0; k < 16; ++k) if (k > i) v -= Ls[s][k][i] * x[k];
      x[i] = v / Ls[s][i][i];
    }
#pragma unroll
    for (int i = 0; i < 16; ++i) prec[s * 256 + i * 16 + col] = x[i];
  }
}

// ---------------------------------------------------------------------------
// emis v7 (r14 proven): state-pair x 4 batches, 512x512, 40 KB LDS,
// 2 blocks/CU = 16 waves/CU. Wave w owns ONE m-tile mt=(w<4?w:11-w).
// ---------------------------------------------------------------------------
__global__ __launch_bounds__(512, 4) void emis_kernel(const float* __restrict__ emis,
                                                      const float* __restrict__ means,
                                                      float* __restrict__ ws) {
  const float* prec   = ws + OFF_PREC;
  const float* logdet = ws + OFF_LOGDET;
  const u16* Wt = (const u16*)(ws + OFF_WT);
  float* ell = ws + OFF_ELL;

  int sp = blockIdx.x & 3;
  int bg = blockIdx.x >> 2;
  int s0 = sp * 2;
  int bb0 = bg * 4;
  int tid = threadIdx.x;

  __shared__ __align__(16) char smem[40960];     // padh[4][256][16] u16 (32 KB)
  char* pbase = smem;                            // ... then diffL[4][128][20] f32
  float* dlf = (float*)smem;
  const s16x8 zero8 = {0, 0, 0, 0, 0, 0, 0, 0};

  for (int i = tid; i < 1024; i += 512)          // zero rows 0..127, 4 planes
    *(s16x8*)(pbase + (i >> 8) * 8192 + (i & 255) * 16) = zero8;
  for (int i = tid; i < 1024; i += 512) {        // stage rows 128..255, swizzled
    int g = i >> 8, erow = (i >> 1) & 127, h2 = i & 1;
    const f32x4* src = (const f32x4*)(emis + (size_t)(bb0 + g) * 2048 + erow * 16 + h2 * 8);
    f32x4 v0 = src[0], v1 = src[1];
    s16x8 pk;
#pragma unroll
    for (int c = 0; c < 4; ++c) { pk[c] = (short)f2bf(v0[c]); pk[c + 4] = (short)f2bf(v1[c]); }
    int row = 128 + erow;
    int off = ((row << 5) + (h2 << 4)) ^ (((row >> 2) & 3) << 4);
    *(s16x8*)(pbase + g * 8192 + off) = pk;
  }
  __syncthreads();

  int wave = tid >> 6, lane = tid & 63;
  int mt = (wave < 4) ? wave : 11 - wave;        // balanced SIMD pairing
  int rc = lane & 15;
  int h  = (lane >> 4) & 1;
  int dl = lane >> 5;
  int hh = h << 4;
  int kst = 56 - 8 * mt;
  int r0 = mt * 16 + rc + dl;

  const u16* Bp0 = Wt + ((size_t)((s0 * 128 + dl) * 16 + rc) * 16) + h * 8 + (size_t)kst * 512;
  const u16* Bp1 = Bp0 + 32768;

  f32x4 acc[2][4] = {};
  s16x8 w0 = *(const s16x8*)Bp0, w1 = *(const s16x8*)Bp1;
  for (int kk = kst; kk < 64; ++kk) {
    s16x8 n0, n1;
    if (kk < 63) { n0 = *(const s16x8*)(Bp0 + 512); n1 = *(const s16x8*)(Bp1 + 512); }
    Bp0 += 512; Bp1 += 512;
    int row = r0 + 2 * kk;
    const char* pa = pbase + (((row << 5) + hh) ^ (((row >> 2) & 3) << 4));
#pragma unroll
    for (int g = 0; g < 4; ++g) {
      s16x8 a = *(const s16x8*)(pa + g * 8192);
      acc[0][g] = __builtin_amdgcn_mfma_f32_16x16x32_bf16(a, w0, acc[0][g], 0, 0, 0);
      acc[1][g] = __builtin_amdgcn_mfma_f32_16x16x32_bf16(a, w1, acc[1][g], 0, 0, 0);
    }
    w0 = n0; w1 = n1;
  }

  int hi = (lane >> 4) & 3;
  float ev[4][4];
#pragma unroll
  for (int g = 0; g < 4; ++g)
#pragma unroll
    for (int r = 0; r < 4; ++r)
      ev[g][r] = emis[(size_t)(bb0 + g) * 2048 + (mt * 16 + hi * 4 + r) * 16 + rc];

  __syncthreads();                               // Hankel tile dead -> overlay diffL

#pragma unroll
  for (int s = 0; s < 2; ++s) {
    float mn = means[(s0 + s) * 16 + rc];
#pragma unroll
    for (int g = 0; g < 4; ++g) {
#pragma unroll
      for (int r = 0; r < 4; ++r) {
        int f = mt * 16 + hi * 4 + r;
        dlf[(g * 128 + f) * 20 + rc] = ev[g][r] - acc[s][g][r] - mn;
      }
    }
    __syncthreads();
    const float* P = prec + (s0 + s) * 256;      // block-uniform -> scalar loads
    float c2 = -0.72134752f * (logdet[s0 + s] + 16.f * LOG2PI_F);
    {
      int g = tid >> 7, f = tid & 127;           // 512 tasks = 4 batches x 128 f
      float dv[16];
#pragma unroll
      for (int c = 0; c < 4; ++c)
        *(f32x4*)&dv[c * 4] = *(const f32x4*)&dlf[(g * 128 + f) * 20 + c * 4];
      float qq = 0.f;
#pragma unroll
      for (int c = 0; c < 16; ++c) {
        float tsum = 0.5f * P[c * 16 + c] * dv[c];
#pragma unroll
        for (int d2 = 0; d2 < 16; ++d2)
          if (d2 > c) tsum = fmaf(P[c * 16 + d2], dv[d2], tsum);
        qq = fmaf(dv[c], tsum, qq);
      }
      ell[((size_t)(bb0 + g) * 8 + s0 + s) * 128 + f] = fmaf(-2.f * 0.72134752f, qq, c2);
    }
    if (s == 0) __syncthreads();
  }
}

// ---------------------------------------------------------------------------
// fwd v8 (r19): linear tree, row-per-thread, exponent rescale; terminal
// plain flag[b] store (no atomics).
// ---------------------------------------------------------------------------
__global__ __launch_bounds__(256) void fwd_kernel(float* __restrict__ ws) {
  const float* ell  = ws + OFF_ELL;
  const float* ltr  = ws + OFF_LTR;
  const float* lini = ws + OFF_LINI;
  int* flag = (int*)(ws + OFF_FLAG);

  __shared__ float leaf[128 * 68];     // 34 KB (stride-68 matrices)
  __shared__ float lvl[64 * 68];       // 17 KB
  __shared__ float ebuf[1024];         // 4 KB: ell[b] = [s][f]
  __shared__ float LTs[64];
  __shared__ float kmax[128];
  __shared__ float redv[8];

  int b = blockIdx.x, tid = threadIdx.x;

  *(f32x4*)&ebuf[tid * 4] = *(const f32x4*)(ell + (size_t)b * 1024 + tid * 4);
  if (tid < 64) LTs[tid] = ltr[tid];
  __syncthreads();

  if (tid < 128) {                     // per-leaf column max (leaf m uses e_{m+1})
    int m = tid;
    float mx = 0.f;
    if (m < 127) {
      mx = -1e30f;
#pragma unroll
      for (int j = 0; j < 8; ++j) mx = fmaxf(mx, ebuf[j * 128 + m + 1]);
    }
    kmax[m] = mx;
  }
  __syncthreads();

  for (int t = tid; t < 8192; t += 256) {   // leaves (linear, exp2 here only)
    int m = t >> 6, i = (t >> 3) & 7, j = t & 7;
    float v;
    if (m < 127) v = fexp2(LTs[i * 8 + j] + ebuf[j * 128 + (m + 1)] - kmax[m]);
    else         v = (i == j) ? 1.f : 0.f;  // identity pad
    leaf[m * 68 + i * 8 + j] = v;
  }
  __syncthreads();

  float* src = leaf;
  float* dst = lvl;
  int nm = 64;
  for (int level = 0; level < 7; ++level) {
    for (int t = tid; t < nm * 8; t += 256) {   // task = one output ROW
      int p = t >> 3, i = t & 7;
      const float* Ma = src + (p * 2) * 68 + i * 8;
      const float* Mb = src + (p * 2 + 1) * 68;
      float av[8];
      *(f32x4*)&av[0] = *(const f32x4*)&Ma[0];
      *(f32x4*)&av[4] = *(const f32x4*)&Ma[4];
      float B[8][8];                            // 64 VGPR, static-indexed
#pragma unroll
      for (int k = 0; k < 8; ++k) {
        *(f32x4*)&B[k][0] = *(const f32x4*)&Mb[k * 8];
        *(f32x4*)&B[k][4] = *(const f32x4*)&Mb[k * 8 + 4];
      }
      float outv[8];
#pragma unroll
      for (int j = 0; j < 8; ++j) {
        float sum = 0.f;
#pragma unroll
        for (int k = 0; k < 8; ++k) sum = fmaf(av[k], B[k][j], sum);
        outv[j] = sum;
      }
      // per-matrix rescale: rows of matrix p live in an aligned 8-lane group
      float rm = outv[0];
#pragma unroll
      for (int j = 1; j < 8; ++j) rm = fmaxf(rm, outv[j]);
      rm = fmaxf(rm, __shfl_xor(rm, 1));
      rm = fmaxf(rm, __shfl_xor(rm, 2));
      rm = fmaxf(rm, __shfl_xor(rm, 4));
      int ex = (int)((__float_as_uint(rm) >> 23) & 0xFFu) - 127;
#pragma unroll
      for (int j = 0; j < 8; ++j) outv[j] = ldexpf(outv[j], -ex);
      *(f32x4*)&dst[p * 68 + i * 8]     = *(f32x4*)&outv[0];
      *(f32x4*)&dst[p * 68 + i * 8 + 4] = *(f32x4*)&outv[4];
    }
    __syncthreads();
    float* tswap = src; src = dst; dst = tswap;
    nm >>= 1;
  }
  // rescaled product matrix P in src[0..63]

  if (tid < 8) {                        // v[s] = sum_i exp2(la0[i]-k0) * P[i][s]
    int s = tid;
    float k0 = -1e30f;
#pragma unroll
    for (int i = 0; i < 8; ++i) k0 = fmaxf(k0, lini[i] + ebuf[i * 128]);
    float v = 0.f;
#pragma unroll
    for (int i = 0; i < 8; ++i)
      v = fmaf(fexp2(lini[i] + ebuf[i * 128] - k0), src[i * 8 + s], v);
    redv[s] = v;
  }
  __syncthreads();
  if (tid == 0) {
    float best = -1e30f; int bi = 0;
#pragma unroll
    for (int i = 0; i < 8; ++i) {
      float o = redv[i];
      if (o > best) { best = o; bi = i; }   // first-max (monotone map preserves)
    }
    flag[b] = bi;                           // plain store; no atomic
  }
}

// ---------------------------------------------------------------------------
// bucket v2: wave-parallel ballot bucketing. 8 waves, wave w owns bucket w;
// per 64-batch chunk: ballot mask -> popc rank -> direct perm write.
// Deterministic (batch-ascending per bucket), ~1-2 us. r19's serial-lane
// loop was 41 us (LDS-latency-bound, 56/64 lanes idle).
// ---------------------------------------------------------------------------
__global__ __launch_bounds__(512) void bucket_kernel(float* __restrict__ ws) {
  const int* flag = (const int*)(ws + OFF_FLAG);
  int* cnt  = (int*)(ws + OFF_CNT);
  int* perm = (int*)(ws + OFF_PERM);
  int tid = threadIdx.x;
  int w = tid >> 6, lane = tid & 63;
  int base = 0;
#pragma unroll
  for (int c = 0; c < 8; ++c) {
    int b = c * 64 + lane;
    int fl = flag[b];
    unsigned long long mask = __ballot(fl == w);
    int rank = __popcll(mask & ((1ull << lane) - 1ull));
    if (fl == w) perm[w * 512 + base + rank] = b;
    base += __popcll(mask);
  }
  if (lane == 0) cnt[w] = base;
}

// ---------------------------------------------------------------------------
// pred v4 (r14 proven): 8-wave split-K, registers hold outputs.
// ---------------------------------------------------------------------------
__global__ __launch_bounds__(512, 2) void pred_kernel(const float* __restrict__ emis,
                                                      const float* __restrict__ means,
                                                      float* __restrict__ ws,
                                                      float* __restrict__ out) {
  const int* chain = (const int*)(ws + OFF_CHAIN);
  const int* cnt   = (const int*)(ws + OFF_CNT);
  const int* perm  = (const int*)(ws + OFF_PERM);
  const u16* Wt = (const u16*)(ws + OFF_WT);

  __shared__ u16 buf[16][128][16];     // 64 KB bf16 lag buffers, batch-XOR swizzled
  __shared__ float part[8][64][4];     // 8 KB wave partials
  __shared__ float ms[8][16];
  __shared__ int bid[16];

  int bucket = blockIdx.x >> 5, slot = blockIdx.x & 31;
  int nb = cnt[bucket];
  int base = slot * 16;
  if (base >= nb) return;              // block-uniform -> safe before barriers
  int tid = threadIdx.x;
  char* pb = (char*)&buf[0][0][0];

  if (tid < 16) {
    int idx = base + tid;
    bid[tid] = perm[bucket * 512 + (idx < nb ? idx : base)];  // pad = dup first
  } else if (tid >= 128 && tid < 256) {
    int t2 = tid - 128;
    ms[t2 >> 4][t2 & 15] = means[t2];
  }
  __syncthreads();

  for (int i = tid; i < 2048; i += 512) {
    int b = i >> 7, row = i & 127;
    const f32x4* sp = (const f32x4*)(emis + (size_t)bid[b] * 2048 + row * 16);
    f32x4 v0 = sp[0], v1 = sp[1], v2 = sp[2], v3 = sp[3];
    s16x8 p0, p1;
#pragma unroll
    for (int j = 0; j < 4; ++j) {
      p0[j] = (short)f2bf(v0[j]); p0[4 + j] = (short)f2bf(v1[j]);
      p1[j] = (short)f2bf(v2[j]); p1[4 + j] = (short)f2bf(v3[j]);
    }
    int xo = (b & 7) << 4;
    int bse = b * 4096 + row * 32;
    *(s16x8*)(pb + (bse ^ xo)) = p0;
    *(s16x8*)(pb + ((bse + 16) ^ xo)) = p1;
  }
  __syncthreads();

  int wave = tid >> 6, lane = tid & 63;
  int rc = lane & 15;                  // A: batch | B/C: d
  int q  = lane >> 4;
  int h  = q & 1;
  int dl = q >> 1;
  int axor = (rc & 7) << 4;
  const int* mychain = chain + bucket * 16;
  int b_own = q * 4 + (wave & 3);      // waves 0..3 own outputs
  int bown_base = b_own * 4096;
  int bown_xor = (b_own & 7) << 4;

  float outv[16];
  int start = 0;
#pragma unroll
  for (int k = 0; k < 16; ++k) {
    int st = mychain[k];
    const u16* Bb = Wt + ((size_t)((st * 128 + dl) * 16 + rc) * 16) + h * 8;
    f32x4 accA = {0.f, 0.f, 0.f, 0.f}, accB = {0.f, 0.f, 0.f, 0.f};
#pragma unroll
    for (int t2 = 0; t2 < 4; ++t2) {
      int kkA = wave * 8 + t2 * 2, kkB = kkA + 1;
      s16x8 wA = *(const s16x8*)(Bb + (size_t)kkA * 512);
      s16x8 wB2 = *(const s16x8*)(Bb + (size_t)kkB * 512);
      int rowA = (start + kkA * 2 + dl) & 127;
      int rowB = (start + kkB * 2 + dl) & 127;
      s16x8 aA = *(const s16x8*)(pb + ((rc * 4096 + rowA * 32 + h * 16) ^ axor));
      s16x8 aB = *(const s16x8*)(pb + ((rc * 4096 + rowB * 32 + h * 16) ^ axor));
      accA = __builtin_amdgcn_mfma_f32_16x16x32_bf16(aA, wA, accA, 0, 0, 0);
      accB = __builtin_amdgcn_mfma_f32_16x16x32_bf16(aB, wB2, accB, 0, 0, 0);
    }
    f32x4 acc = accA + accB;
    *(f32x4*)&part[wave][lane][0] = acc;
    __syncthreads();
    if (wave < 4) {
      f32x4 cs = (*(f32x4*)&part[0][lane][0] + *(f32x4*)&part[1][lane][0])
               + (*(f32x4*)&part[2][lane][0] + *(f32x4*)&part[3][lane][0]);
      f32x4 cs2 = (*(f32x4*)&part[4][lane][0] + *(f32x4*)&part[5][lane][0])
                + (*(f32x4*)&part[6][lane][0] + *(f32x4*)&part[7][lane][0]);
      cs = cs + cs2;
      float vown = (wave & 3) == 0 ? cs[0] : (wave & 3) == 1 ? cs[1]
                 : (wave & 3) == 2 ? cs[2] : cs[3];
      float o = vown + ms[st][rc];
      outv[k] = o;
      *(u16*)(pb + ((bown_base + start * 32 + rc * 2) ^ bown_xor)) = f2bf(o);
    }
    __syncthreads();
    start = (start + 1) & 127;
  }
  if (wave < 4 && base + b_own < nb) {
    float* op = out + (size_t)bid[b_own] * 256 + rc;
#pragma unroll
    for (int k = 0; k < 16; ++k) op[k * 16] = outv[k];
  }
}

extern "C" void kernel_launch(void* const* d_in, const int* in_sizes, int n_in,
                              void* d_out, int out_size, void* d_ws, size_t ws_size,
                              hipStream_t stream) {
  const float* emis  = (const float*)d_in[0];
  const float* tmat  = (const float*)d_in[1];
  const float* initd = (const float*)d_in[2];
  const float* means = (const float*)d_in[3];
  const float* cc    = (const float*)d_in[4];
  const float* W     = (const float*)d_in[5];
  float* ws  = (float*)d_ws;
  float* out = (float*)d_out;

  hipLaunchKernelGGL(prep_wt_kernel, dim3(1025), dim3(256), 0, stream, tmat, initd, cc, W, ws);
  hipLaunchKernelGGL(emis_kernel, dim3(512), dim3(512), 0, stream, emis, means, ws);
  hipLaunchKernelGGL(fwd_kernel, dim3(512), dim3(256), 0, stream, ws);
  hipLaunchKernelGGL(bucket_kernel, dim3(1), dim3(512), 0, stream, ws);
  hipLaunchKernelGGL(pred_kernel, dim3(256), dim3(512), 0, stream, emis, means, ws, out);
}

// Round 21
// 70.668 us; speedup vs baseline: 1.4462x; 1.0217x over previous
//
#include <hip/hip_runtime.h>
#include <hip/hip_bf16.h>

#define LOG2PI_F 1.8378770664093453f
#define LOG2E_F  1.44269504f

typedef float f32x4 __attribute__((ext_vector_type(4)));
typedef short s16x8 __attribute__((ext_vector_type(8)));
typedef unsigned short u16;

// ---- workspace layout (float offsets into d_ws) ----
#define OFF_PREC   0        // f32 [8][16][16]
#define OFF_LOGDET 2048     // f32 [8]
#define OFF_LTR    2064     // f32 [8][8]   log(softmax(T)+1e-8) * log2e
#define OFF_LINI   2128     // f32 [8]      log softmax(init)    * log2e
#define OFF_CHAIN  2144     // int [8][16]
#define OFF_FLAG   6656     // int [512]    per-batch argmax state
#define OFF_ELL    8192     // f32 [512][8][128]  (scaled by log2e)  [b][s][f]
#define OFF_WT     532480   // u16(bf16) [8][128][16][16]  Wt[s][l][d][c]

__device__ inline u16 f2bf(float x) {
  union { float f; unsigned u; } v; v.f = x;
  unsigned r = v.u + 0x7fffu + ((v.u >> 16) & 1u);  // RNE
  return (u16)(r >> 16);
}

__device__ inline float fexp2(float x) {
#if __has_builtin(__builtin_amdgcn_exp2f)
  return __builtin_amdgcn_exp2f(x);          // raw v_exp_f32
#else
  return exp2f(x);
#endif
}

// ---------------------------------------------------------------------------
// kernel 1: blocks 0..1023 build Wt(bf16); block 1024 does prep (eps-free:
// prec = C^-T C^-1, logdet = 2*sum(diag cc))
// ---------------------------------------------------------------------------
__global__ __launch_bounds__(256) void prep_wt_kernel(const float* __restrict__ tmat,
                                                      const float* __restrict__ initd,
                                                      const float* __restrict__ cc,
                                                      const float* __restrict__ W,
                                                      float* __restrict__ ws) {
  __shared__ float Ls[8][16][16];
  __shared__ float tmp[256];
  int t = threadIdx.x;

  if (blockIdx.x < 1024) {                       // ---- Wt build ----
    u16* Wt = (u16*)(ws + OFF_WT);
    int sl = blockIdx.x;
    tmp[t] = W[sl * 256 + t];
    __syncthreads();
    int d = t >> 4, c = t & 15;
    Wt[sl * 256 + t] = f2bf(tmp[c * 16 + d]);    // out[d][c] = in[c][d]
    return;
  }

  // ---- prep ----
  float* prec   = ws + OFF_PREC;
  float* logdet = ws + OFF_LOGDET;
  float* ltr    = ws + OFF_LTR;
  float* lini   = ws + OFF_LINI;
  int*   chain  = (int*)(ws + OFF_CHAIN);

  if (t < 128) {                                 // chol = tril(cc,-1)+diag(exp(diag))
    int s = t >> 4, i = t & 15;
    const float* c0 = cc + s * 256 + i * 16;
    for (int j = 0; j < 16; ++j) {
      float v = c0[j];
      Ls[s][i][j] = (i > j) ? v : (i == j ? expf(v) : 0.f);
    }
  } else if (t < 136) {                          // logdet = 2*sum(diag cc) (eps-free)
    int s = t - 128;
    float ld = 0.f;
    for (int i = 0; i < 16; ++i) ld += cc[s * 256 + i * 17];
    logdet[s] = 2.f * ld;
  } else if (t == 136) {
    float m = -1e30f;
    for (int i = 0; i < 8; ++i) m = fmaxf(m, initd[i]);
    float sum = 0.f;
    for (int i = 0; i < 8; ++i) sum += expf(initd[i] - m);
    float lsum = logf(sum);
    for (int i = 0; i < 8; ++i) lini[i] = (initd[i] - m - lsum) * LOG2E_F;
  } else if (t == 137) {
    int nxt[8];
    for (int i = 0; i < 8; ++i) {
      float best = -1e30f; int bi = 0;
      for (int j = 0; j < 8; ++j) {
        float v = tmat[i * 8 + j];
        if (v > best) { best = v; bi = j; }      // first-max rule
      }
      nxt[i] = bi;
    }
    for (int s0 = 0; s0 < 8; ++s0) {
      int c = s0;
      for (int k = 0; k < 16; ++k) { c = nxt[c]; chain[s0 * 16 + k] = c; }
    }
  } else if (t >= 144 && t < 152) {
    int i = t - 144;
    float m = -1e30f;
    for (int j = 0; j < 8; ++j) m = fmaxf(m, tmat[i * 8 + j]);
    float sum = 0.f;
    for (int j = 0; j < 8; ++j) sum += expf(tmat[i * 8 + j] - m);
    for (int j = 0; j < 8; ++j)
      ltr[i * 8 + j] = logf(expf(tmat[i * 8 + j] - m) / sum + 1e-8f) * LOG2E_F;
  }
  __syncthreads();
  if (t < 128) {                                 // prec = C^-T C^-1
    int s = t >> 4, col = t & 15;
    float y[16], x[16];
#pragma unroll
    for (int i = 0; i < 16; ++i) {
      float v = (i == col) ? 1.f : 0.f;
#pragma unroll
      for (int k = 0; k < 16; ++k) if (k < i) v -= Ls[s][i][k] * y[k];
      y[i] = v / Ls[s][i][i];
    }
#pragma unroll
    for (int i = 15; i >= 0; --i) {
      float v = y[i];
#pragma unroll
      for (int k = 0; k < 16; ++k) if (k > i) v -= Ls[s][k][i] * x[k];
      x[i] = v / Ls[s][i][i];
    }
#pragma unroll
    for (int i = 0; i < 16; ++i) prec[s * 256 + i * 16 + col] = x[i];
  }
}

// ---------------------------------------------------------------------------
// emis v7 (r14 proven): state-pair x 4 batches, 512x512, 40 KB LDS,
// 2 blocks/CU = 16 waves/CU. Wave w owns ONE m-tile mt=(w<4?w:11-w).
// ---------------------------------------------------------------------------
__global__ __launch_bounds__(512, 4) void emis_kernel(const float* __restrict__ emis,
                                                      const float* __restrict__ means,
                                                      float* __restrict__ ws) {
  const float* prec   = ws + OFF_PREC;
  const float* logdet = ws + OFF_LOGDET;
  const u16* Wt = (const u16*)(ws + OFF_WT);
  float* ell = ws + OFF_ELL;

  int sp = blockIdx.x & 3;
  int bg = blockIdx.x >> 2;
  int s0 = sp * 2;
  int bb0 = bg * 4;
  int tid = threadIdx.x;

  __shared__ __align__(16) char smem[40960];     // padh[4][256][16] u16 (32 KB)
  char* pbase = smem;                            // ... then diffL[4][128][20] f32
  float* dlf = (float*)smem;
  const s16x8 zero8 = {0, 0, 0, 0, 0, 0, 0, 0};

  for (int i = tid; i < 1024; i += 512)          // zero rows 0..127, 4 planes
    *(s16x8*)(pbase + (i >> 8) * 8192 + (i & 255) * 16) = zero8;
  for (int i = tid; i < 1024; i += 512) {        // stage rows 128..255, swizzled
    int g = i >> 8, erow = (i >> 1) & 127, h2 = i & 1;
    const f32x4* src = (const f32x4*)(emis + (size_t)(bb0 + g) * 2048 + erow * 16 + h2 * 8);
    f32x4 v0 = src[0], v1 = src[1];
    s16x8 pk;
#pragma unroll
    for (int c = 0; c < 4; ++c) { pk[c] = (short)f2bf(v0[c]); pk[c + 4] = (short)f2bf(v1[c]); }
    int row = 128 + erow;
    int off = ((row << 5) + (h2 << 4)) ^ (((row >> 2) & 3) << 4);
    *(s16x8*)(pbase + g * 8192 + off) = pk;
  }
  __syncthreads();

  int wave = tid >> 6, lane = tid & 63;
  int mt = (wave < 4) ? wave : 11 - wave;        // balanced SIMD pairing
  int rc = lane & 15;
  int h  = (lane >> 4) & 1;
  int dl = lane >> 5;
  int hh = h << 4;
  int kst = 56 - 8 * mt;
  int r0 = mt * 16 + rc + dl;

  const u16* Bp0 = Wt + ((size_t)((s0 * 128 + dl) * 16 + rc) * 16) + h * 8 + (size_t)kst * 512;
  const u16* Bp1 = Bp0 + 32768;

  f32x4 acc[2][4] = {};
  s16x8 w0 = *(const s16x8*)Bp0, w1 = *(const s16x8*)Bp1;
  for (int kk = kst; kk < 64; ++kk) {
    s16x8 n0, n1;
    if (kk < 63) { n0 = *(const s16x8*)(Bp0 + 512); n1 = *(const s16x8*)(Bp1 + 512); }
    Bp0 += 512; Bp1 += 512;
    int row = r0 + 2 * kk;
    const char* pa = pbase + (((row << 5) + hh) ^ (((row >> 2) & 3) << 4));
#pragma unroll
    for (int g = 0; g < 4; ++g) {
      s16x8 a = *(const s16x8*)(pa + g * 8192);
      acc[0][g] = __builtin_amdgcn_mfma_f32_16x16x32_bf16(a, w0, acc[0][g], 0, 0, 0);
      acc[1][g] = __builtin_amdgcn_mfma_f32_16x16x32_bf16(a, w1, acc[1][g], 0, 0, 0);
    }
    w0 = n0; w1 = n1;
  }

  int hi = (lane >> 4) & 3;
  float ev[4][4];
#pragma unroll
  for (int g = 0; g < 4; ++g)
#pragma unroll
    for (int r = 0; r < 4; ++r)
      ev[g][r] = emis[(size_t)(bb0 + g) * 2048 + (mt * 16 + hi * 4 + r) * 16 + rc];

  __syncthreads();                               // Hankel tile dead -> overlay diffL

#pragma unroll
  for (int s = 0; s < 2; ++s) {
    float mn = means[(s0 + s) * 16 + rc];
#pragma unroll
    for (int g = 0; g < 4; ++g) {
#pragma unroll
      for (int r = 0; r < 4; ++r) {
        int f = mt * 16 + hi * 4 + r;
        dlf[(g * 128 + f) * 20 + rc] = ev[g][r] - acc[s][g][r] - mn;
      }
    }
    __syncthreads();
    const float* P = prec + (s0 + s) * 256;      // block-uniform -> scalar loads
    float c2 = -0.72134752f * (logdet[s0 + s] + 16.f * LOG2PI_F);
    {
      int g = tid >> 7, f = tid & 127;           // 512 tasks = 4 batches x 128 f
      float dv[16];
#pragma unroll
      for (int c = 0; c < 4; ++c)
        *(f32x4*)&dv[c * 4] = *(const f32x4*)&dlf[(g * 128 + f) * 20 + c * 4];
      float qq = 0.f;
#pragma unroll
      for (int c = 0; c < 16; ++c) {
        float tsum = 0.5f * P[c * 16 + c] * dv[c];
#pragma unroll
        for (int d2 = 0; d2 < 16; ++d2)
          if (d2 > c) tsum = fmaf(P[c * 16 + d2], dv[d2], tsum);
        qq = fmaf(dv[c], tsum, qq);
      }
      ell[((size_t)(bb0 + g) * 8 + s0 + s) * 128 + f] = fmaf(-2.f * 0.72134752f, qq, c2);
    }
    if (s == 0) __syncthreads();
  }
}

// ---------------------------------------------------------------------------
// fwd v8 (r19/r20): linear tree, row-per-thread, exponent rescale; terminal
// plain flag[b] store (no atomics).
// ---------------------------------------------------------------------------
__global__ __launch_bounds__(256) void fwd_kernel(float* __restrict__ ws) {
  const float* ell  = ws + OFF_ELL;
  const float* ltr  = ws + OFF_LTR;
  const float* lini = ws + OFF_LINI;
  int* flag = (int*)(ws + OFF_FLAG);

  __shared__ float leaf[128 * 68];     // 34 KB (stride-68 matrices)
  __shared__ float lvl[64 * 68];       // 17 KB
  __shared__ float ebuf[1024];         // 4 KB: ell[b] = [s][f]
  __shared__ float LTs[64];
  __shared__ float kmax[128];
  __shared__ float redv[8];

  int b = blockIdx.x, tid = threadIdx.x;

  *(f32x4*)&ebuf[tid * 4] = *(const f32x4*)(ell + (size_t)b * 1024 + tid * 4);
  if (tid < 64) LTs[tid] = ltr[tid];
  __syncthreads();

  if (tid < 128) {                     // per-leaf column max (leaf m uses e_{m+1})
    int m = tid;
    float mx = 0.f;
    if (m < 127) {
      mx = -1e30f;
#pragma unroll
      for (int j = 0; j < 8; ++j) mx = fmaxf(mx, ebuf[j * 128 + m + 1]);
    }
    kmax[m] = mx;
  }
  __syncthreads();

  for (int t = tid; t < 8192; t += 256) {   // leaves (linear, exp2 here only)
    int m = t >> 6, i = (t >> 3) & 7, j = t & 7;
    float v;
    if (m < 127) v = fexp2(LTs[i * 8 + j] + ebuf[j * 128 + (m + 1)] - kmax[m]);
    else         v = (i == j) ? 1.f : 0.f;  // identity pad
    leaf[m * 68 + i * 8 + j] = v;
  }
  __syncthreads();

  float* src = leaf;
  float* dst = lvl;
  int nm = 64;
  for (int level = 0; level < 7; ++level) {
    for (int t = tid; t < nm * 8; t += 256) {   // task = one output ROW
      int p = t >> 3, i = t & 7;
      const float* Ma = src + (p * 2) * 68 + i * 8;
      const float* Mb = src + (p * 2 + 1) * 68;
      float av[8];
      *(f32x4*)&av[0] = *(const f32x4*)&Ma[0];
      *(f32x4*)&av[4] = *(const f32x4*)&Ma[4];
      float B[8][8];                            // 64 VGPR, static-indexed
#pragma unroll
      for (int k = 0; k < 8; ++k) {
        *(f32x4*)&B[k][0] = *(const f32x4*)&Mb[k * 8];
        *(f32x4*)&B[k][4] = *(const f32x4*)&Mb[k * 8 + 4];
      }
      float outv[8];
#pragma unroll
      for (int j = 0; j < 8; ++j) {
        float sum = 0.f;
#pragma unroll
        for (int k = 0; k < 8; ++k) sum = fmaf(av[k], B[k][j], sum);
        outv[j] = sum;
      }
      // per-matrix rescale: rows of matrix p live in an aligned 8-lane group
      float rm = outv[0];
#pragma unroll
      for (int j = 1; j < 8; ++j) rm = fmaxf(rm, outv[j]);
      rm = fmaxf(rm, __shfl_xor(rm, 1));
      rm = fmaxf(rm, __shfl_xor(rm, 2));
      rm = fmaxf(rm, __shfl_xor(rm, 4));
      int ex = (int)((__float_as_uint(rm) >> 23) & 0xFFu) - 127;
#pragma unroll
      for (int j = 0; j < 8; ++j) outv[j] = ldexpf(outv[j], -ex);
      *(f32x4*)&dst[p * 68 + i * 8]     = *(f32x4*)&outv[0];
      *(f32x4*)&dst[p * 68 + i * 8 + 4] = *(f32x4*)&outv[4];
    }
    __syncthreads();
    float* tswap = src; src = dst; dst = tswap;
    nm >>= 1;
  }
  // rescaled product matrix P in src[0..63]

  if (tid < 8) {                        // v[s] = sum_i exp2(la0[i]-k0) * P[i][s]
    int s = tid;
    float k0 = -1e30f;
#pragma unroll
    for (int i = 0; i < 8; ++i) k0 = fmaxf(k0, lini[i] + ebuf[i * 128]);
    float v = 0.f;
#pragma unroll
    for (int i = 0; i < 8; ++i)
      v = fmaf(fexp2(lini[i] + ebuf[i * 128] - k0), src[i * 8 + s], v);
    redv[s] = v;
  }
  __syncthreads();
  if (tid == 0) {
    float best = -1e30f; int bi = 0;
#pragma unroll
    for (int i = 0; i < 8; ++i) {
      float o = redv[i];
      if (o > best) { best = o; bi = i; }   // first-max (monotone map preserves)
    }
    flag[b] = bi;                           // plain store; no atomic
  }
}

// ---------------------------------------------------------------------------
// pred v5: v4 + INLINE bucketing. Wave 0 re-runs the ballot scan over
// flag[512] (2 KB, L2-hot, all blocks in parallel) and keeps only its own
// window [base, base+16) -> bid[] + nb. Removes the 1-block bucket_kernel
// and its launch bubble (~10 us). Deterministic (batch-ascending ordinals).
// ---------------------------------------------------------------------------
__global__ __launch_bounds__(512, 2) void pred_kernel(const float* __restrict__ emis,
                                                      const float* __restrict__ means,
                                                      float* __restrict__ ws,
                                                      float* __restrict__ out) {
  const int* chain = (const int*)(ws + OFF_CHAIN);
  const int* flag  = (const int*)(ws + OFF_FLAG);
  const u16* Wt = (const u16*)(ws + OFF_WT);

  __shared__ u16 buf[16][128][16];     // 64 KB bf16 lag buffers, batch-XOR swizzled
  __shared__ float part[8][64][4];     // 8 KB wave partials
  __shared__ float ms[8][16];
  __shared__ int bid[16];
  __shared__ int nb_sh;

  int bucket = blockIdx.x >> 5, slot = blockIdx.x & 31;
  int base = slot * 16;
  int tid = threadIdx.x;
  char* pb = (char*)&buf[0][0][0];

  if (tid < 64) {                      // wave 0: ballot bucketing for my window
    int lane = tid;
    if (lane < 16) bid[lane] = -1;     // same-wave LDS ordering
    int cbase = 0;
#pragma unroll
    for (int c = 0; c < 8; ++c) {
      int b = c * 64 + lane;
      int fl = flag[b];
      unsigned long long mask = __ballot(fl == bucket);
      int rank = __popcll(mask & ((1ull << lane) - 1ull));
      int ord = cbase + rank;
      if (fl == bucket && ord >= base && ord < base + 16) bid[ord - base] = b;
      cbase += __popcll(mask);
    }
    if (lane == 0) nb_sh = cbase;
  } else if (tid >= 128 && tid < 256) {
    int t2 = tid - 128;
    ms[t2 >> 4][t2 & 15] = means[t2];
  }
  __syncthreads();
  int nb = nb_sh;
  if (base >= nb) return;              // block-uniform, all threads past barrier
  if (tid < 16 && bid[tid] < 0) bid[tid] = bid[0];   // pad = dup first (set: base<nb)
  __syncthreads();

  for (int i = tid; i < 2048; i += 512) {
    int b = i >> 7, row = i & 127;
    const f32x4* sp = (const f32x4*)(emis + (size_t)bid[b] * 2048 + row * 16);
    f32x4 v0 = sp[0], v1 = sp[1], v2 = sp[2], v3 = sp[3];
    s16x8 p0, p1;
#pragma unroll
    for (int j = 0; j < 4; ++j) {
      p0[j] = (short)f2bf(v0[j]); p0[4 + j] = (short)f2bf(v1[j]);
      p1[j] = (short)f2bf(v2[j]); p1[4 + j] = (short)f2bf(v3[j]);
    }
    int xo = (b & 7) << 4;
    int bse = b * 4096 + row * 32;
    *(s16x8*)(pb + (bse ^ xo)) = p0;
    *(s16x8*)(pb + ((bse + 16) ^ xo)) = p1;
  }
  __syncthreads();

  int wave = tid >> 6, lane = tid & 63;
  int rc = lane & 15;                  // A: batch | B/C: d
  int q  = lane >> 4;
  int h  = q & 1;
  int dl = q >> 1;
  int axor = (rc & 7) << 4;
  const int* mychain = chain + bucket * 16;
  int b_own = q * 4 + (wave & 3);      // waves 0..3 own outputs
  int bown_base = b_own * 4096;
  int bown_xor = (b_own & 7) << 4;

  float outv[16];
  int start = 0;
#pragma unroll
  for (int k = 0; k < 16; ++k) {
    int st = mychain[k];
    const u16* Bb = Wt + ((size_t)((st * 128 + dl) * 16 + rc) * 16) + h * 8;
    f32x4 accA = {0.f, 0.f, 0.f, 0.f}, accB = {0.f, 0.f, 0.f, 0.f};
#pragma unroll
    for (int t2 = 0; t2 < 4; ++t2) {
      int kkA = wave * 8 + t2 * 2, kkB = kkA + 1;
      s16x8 wA = *(const s16x8*)(Bb + (size_t)kkA * 512);
      s16x8 wB2 = *(const s16x8*)(Bb + (size_t)kkB * 512);
      int rowA = (start + kkA * 2 + dl) & 127;
      int rowB = (start + kkB * 2 + dl) & 127;
      s16x8 aA = *(const s16x8*)(pb + ((rc * 4096 + rowA * 32 + h * 16) ^ axor));
      s16x8 aB = *(const s16x8*)(pb + ((rc * 4096 + rowB * 32 + h * 16) ^ axor));
      accA = __builtin_amdgcn_mfma_f32_16x16x32_bf16(aA, wA, accA, 0, 0, 0);
      accB = __builtin_amdgcn_mfma_f32_16x16x32_bf16(aB, wB2, accB, 0, 0, 0);
    }
    f32x4 acc = accA + accB;
    *(f32x4*)&part[wave][lane][0] = acc;
    __syncthreads();
    if (wave < 4) {
      f32x4 cs = (*(f32x4*)&part[0][lane][0] + *(f32x4*)&part[1][lane][0])
               + (*(f32x4*)&part[2][lane][0] + *(f32x4*)&part[3][lane][0]);
      f32x4 cs2 = (*(f32x4*)&part[4][lane][0] + *(f32x4*)&part[5][lane][0])
                + (*(f32x4*)&part[6][lane][0] + *(f32x4*)&part[7][lane][0]);
      cs = cs + cs2;
      float vown = (wave & 3) == 0 ? cs[0] : (wave & 3) == 1 ? cs[1]
                 : (wave & 3) == 2 ? cs[2] : cs[3];
      float o = vown + ms[st][rc];
      outv[k] = o;
      *(u16*)(pb + ((bown_base + start * 32 + rc * 2) ^ bown_xor)) = f2bf(o);
    }
    __syncthreads();
    start = (start + 1) & 127;
  }
  if (wave < 4 && base + b_own < nb) {
    float* op = out + (size_t)bid[b_own] * 256 + rc;
#pragma unroll
    for (int k = 0; k < 16; ++k) op[k * 16] = outv[k];
  }
}

extern "C" void kernel_launch(void* const* d_in, const int* in_sizes, int n_in,
                              void* d_out, int out_size, void* d_ws, size_t ws_size,
                              hipStream_t stream) {
  const float* emis  = (const float*)d_in[0];
  const float* tmat  = (const float*)d_in[1];
  const float* initd = (const float*)d_in[2];
  const float* means = (const float*)d_in[3];
  const float* cc    = (const float*)d_in[4];
  const float* W     = (const float*)d_in[5];
  float* ws  = (float*)d_ws;
  float* out = (float*)d_out;

  hipLaunchKernelGGL(prep_wt_kernel, dim3(1025), dim3(256), 0, stream, tmat, initd, cc, W, ws);
  hipLaunchKernelGGL(emis_kernel, dim3(512), dim3(512), 0, stream, emis, means, ws);
  hipLaunchKernelGGL(fwd_kernel, dim3(512), dim3(256), 0, stream, ws);
  hipLaunchKernelGGL(pred_kernel, dim3(256), dim3(512), 0, stream, emis, means, ws, out);
}